// Round 8
// baseline (478.902 us; speedup 1.0000x reference)
//
#include <hip/hip_runtime.h>
#include <math.h>

#define LN_EPS 1e-5f
#define NWAVE 8
#define TPB 512
#define ROWS_PER_BLOCK 128   // 8 waves x 16 rows
#define HSTRIDE 72           // halves; 144B row stride (16B-aligned)

typedef _Float16 half8 __attribute__((ext_vector_type(8)));
typedef float f32x4 __attribute__((ext_vector_type(4)));

// weight-fragment table offsets (in halves); each fragment = 512 halves (64 lanes x 8)
#define OFF_W1   0        // [128x192] = kW1|vW1|rW1[0:128] centered, KB=4 -> 48 frags
#define OFF_KW2  24576    // [64x32] KB=2 CB=2 -> 4 frags
#define OFF_VW2  26624
#define OFF_RW2  28672    // centered
#define OFF_QW2  30720    // [16->pad32 x 32] KB=1 CB=2 (rows 16-31 zero)
#define OFF_AW1  31744    // [32x32] KB=1 CB=2, centered
#define OFF_AW2  32768    // [32x16] KB=1 CB=1
#define OFF_RW3  33280
#define OFF_GW1  33792    // centered
#define OFF_GW2  34304    // [16->pad32 x 3->pad16] zeros outside valid region
#define WL_HALVES 34816

__device__ _Float16 g_wfrag[WL_HALVES];  // L2-resident weight-fragment table (68 KB)
__device__ float g_rw1p[3 * 64];         // centered rW1 rows 128..130 (f32)
__device__ float g_qw1c[3 * 16];         // centered qW1 (f32)

__device__ __forceinline__ f32x4 mfma16(half8 a, half8 b, f32x4 c) {
  return __builtin_amdgcn_mfma_f32_16x16x32_f16(a, b, c, 0, 0, 0);
}

// ---- DPP 16-lane sum (pure VALU; proven R5-R7) ----
template<int CTRL>
__device__ __forceinline__ float dpp_mov(float x) {
  int xi = __builtin_bit_cast(int, x);
  int yi = __builtin_amdgcn_update_dpp(xi, xi, CTRL, 0xF, 0xF, false);
  return __builtin_bit_cast(float, yi);
}
__device__ __forceinline__ float red16_sum(float x) {
  x += dpp_mov<0xB1>(x);    // xor1: quad_perm(1,0,3,2)
  x += dpp_mov<0x4E>(x);    // xor2: quad_perm(2,3,0,1)
  x += dpp_mov<0x141>(x);   // xor4: ROW_HALF_MIRROR
  x += dpp_mov<0x140>(x);   // xor8: ROW_MIRROR
  return x;
}

// fp32 [K][N] row-major weight -> B-fragment order; optional per-k-row column-mean
// centering (valid because every LN input is a bias-free linear output).
__device__ __forceinline__ void pack_frag(const float* __restrict__ W,
    int Ksrc, int Nsrc, int Kpad, int Npad, int KBdst, int cb_off,
    int off, int gtid, int gstride, bool center) {
  int tot = Kpad * Npad;
  float rn = 1.f / (float)Nsrc;
  for (int idx = gtid; idx < tot; idx += gstride) {
    int k = idx / Npad;
    int c = idx - k * Npad;
    float v = 0.f;
    if (k < Ksrc && c < Nsrc) {
      v = W[k * Nsrc + c];
      if (center) {
        float m = 0.f;
        for (int c2 = 0; c2 < Nsrc; ++c2) m += W[k * Nsrc + c2];
        v -= m * rn;
      }
    }
    int cb = cb_off + (c >> 4);
    int lanei = ((k >> 3) & 3) * 16 + (c & 15);
    int dst = off + ((cb * KBdst + (k >> 5)) * 64 + lanei) * 8 + (k & 7);
    g_wfrag[dst] = (_Float16)v;
  }
}

__global__ void prepack_kernel(const float* kW1, const float* vW1, const float* rW1,
                               const float* kW2, const float* vW2, const float* rW2,
                               const float* qW1, const float* qW2, const float* aW1,
                               const float* aW2, const float* rW3, const float* gW1,
                               const float* gW2) {
  int gtid = blockIdx.x * blockDim.x + threadIdx.x;
  int gstride = gridDim.x * blockDim.x;
  pack_frag(kW1, 128, 64, 128, 64, 4, 0, OFF_W1, gtid, gstride, true);
  pack_frag(vW1, 128, 64, 128, 64, 4, 4, OFF_W1, gtid, gstride, true);
  pack_frag(rW1, 128, 64, 128, 64, 4, 8, OFF_W1, gtid, gstride, true);  // rows 0..127
  pack_frag(kW2, 64, 32, 64, 32, 2, 0, OFF_KW2, gtid, gstride, false);
  pack_frag(vW2, 64, 32, 64, 32, 2, 0, OFF_VW2, gtid, gstride, false);
  pack_frag(rW2, 64, 32, 64, 32, 2, 0, OFF_RW2, gtid, gstride, true);
  pack_frag(qW2, 16, 32, 32, 32, 1, 0, OFF_QW2, gtid, gstride, false);
  pack_frag(aW1, 32, 32, 32, 32, 1, 0, OFF_AW1, gtid, gstride, true);
  pack_frag(aW2, 32, 16, 32, 16, 1, 0, OFF_AW2, gtid, gstride, false);
  pack_frag(rW3, 32, 16, 32, 16, 1, 0, OFF_RW3, gtid, gstride, false);
  pack_frag(gW1, 32, 16, 32, 16, 1, 0, OFF_GW1, gtid, gstride, true);
  pack_frag(gW2, 16, 3, 32, 16, 1, 0, OFF_GW2, gtid, gstride, false);
  // centered rW1 param rows 128..130 (over the row's 64 cols)
  for (int i = gtid; i < 3 * 64; i += gstride) {
    int k = 128 + i / 64, c = i - (i / 64) * 64;
    float m = 0.f;
    for (int c2 = 0; c2 < 64; ++c2) m += rW1[k * 64 + c2];
    g_rw1p[i] = rW1[k * 64 + c] - m * (1.f / 64.f);
  }
  // centered qW1 (over 16 cols)
  for (int i = gtid; i < 3 * 16; i += gstride) {
    int k = i / 16, c = i - (i / 16) * 16;
    float m = 0.f;
    for (int c2 = 0; c2 < 16; ++c2) m += qW1[k * 16 + c2];
    g_qw1c[i] = qW1[k * 16 + c] - m * (1.f / 16.f);
  }
}

__global__ __launch_bounds__(TPB, 5)
void approach_mfma_kernel(
    const float* __restrict__ rep, const float* __restrict__ par,
    const float* __restrict__ kg1, const float* __restrict__ kb1, const float* __restrict__ kb2,
    const float* __restrict__ qg1, const float* __restrict__ qb1, const float* __restrict__ qb2,
    const float* __restrict__ vg1, const float* __restrict__ vb1, const float* __restrict__ vb2,
    const float* __restrict__ ag1, const float* __restrict__ ab1, const float* __restrict__ ab2,
    const float* __restrict__ rg1, const float* __restrict__ rb1,
    const float* __restrict__ rg2, const float* __restrict__ rb2, const float* __restrict__ rb3,
    const float* __restrict__ gg1, const float* __restrict__ gb1, const float* __restrict__ gb2,
    float* __restrict__ out, int N)
{
  __shared__ __align__(16) _Float16 hs[NWAVE][16][HSTRIDE];

  const int tid = threadIdx.x;
  const int wave = tid >> 6;
  const int lane = tid & 63;
  const int lo = lane & 15;     // A-row / D-col / B-col index
  const int g4 = lane >> 4;     // k-subblock / D-row group
  const long long row0 = (long long)blockIdx.x * ROWS_PER_BLOCK + wave * 16;
  if (row0 + 16 > N) return;

  _Float16* hw = &hs[wave][0][0];  // [16][HSTRIDE]

  auto ldb = [&](int off, int frag) -> half8 {
    return *reinterpret_cast<const half8*>(&g_wfrag[off + frag * 512 + lane * 8]);
  };
  auto lda = [&](int kb) -> half8 {
    return *reinterpret_cast<const half8*>(&hw[lo * HSTRIDE + kb * 32 + g4 * 8]);
  };
  const f32x4 z4 = {0.f, 0.f, 0.f, 0.f};

  // LN (mean-free: inputs centered by construction) + affine + ReLU, D-layout -> f16 LDS
  auto ln_write = [&](const f32x4* acc, int CB, const float* __restrict__ g,
                      const float* __restrict__ b) {
#pragma unroll 4
    for (int r = 0; r < 4; ++r) {
      float q = 0.f;
      for (int cb = 0; cb < CB; ++cb) { float x = acc[cb][r]; q = fmaf(x, x, q); }
      q = red16_sum(q);
      float rstd = rsqrtf(q * (1.f / (16.f * CB)) + LN_EPS);
      for (int cb = 0; cb < CB; ++cb) {
        float h = fmaxf(fmaf(acc[cb][r] * rstd, g[cb * 16 + lo], b[cb * 16 + lo]), 0.f);
        hw[(g4 * 4 + r) * HSTRIDE + cb * 16 + lo] = (_Float16)h;
      }
    }
  };

  // ---- x A-fragments: row = row0 + lo, k = kb*32 + g4*8 + j
  half8 xa[4];
  {
    const float* xr = rep + (size_t)(row0 + lo) * 128 + g4 * 8;
#pragma unroll
    for (int kb = 0; kb < 4; ++kb) {
      f32x4 u0 = *reinterpret_cast<const f32x4*>(xr + kb * 32);
      f32x4 u1 = *reinterpret_cast<const f32x4*>(xr + kb * 32 + 4);
      half8 h;
#pragma unroll
      for (int j = 0; j < 4; ++j) { h[j] = (_Float16)u0[j]; h[4 + j] = (_Float16)u1[j]; }
      xa[kb] = h;
    }
  }

  // ---- parameters for this tile's D-rows (row = row0 + g4*4 + r)
  float pv[4][3];
#pragma unroll
  for (int r = 0; r < 4; ++r) {
    size_t prow = (size_t)(row0 + g4 * 4 + r) * 3;
#pragma unroll
    for (int i = 0; i < 3; ++i) pv[r][i] = par[prow + i];
  }

  f32x4 kk[2], vv[2], r16v;

  // ======== k / v / residual towers (looped: 1/3 the code) ========
#pragma unroll 1
  for (int tw = 0; tw < 3; ++tw) {
    const float* g1 = tw == 0 ? kg1 : (tw == 1 ? vg1 : rg1);
    const float* b1 = tw == 0 ? kb1 : (tw == 1 ? vb1 : rb1);
    const int w2off = tw == 0 ? OFF_KW2 : (tw == 1 ? OFF_VW2 : OFF_RW2);

    f32x4 acc[4] = {z4, z4, z4, z4};
#pragma unroll
    for (int cb = 0; cb < 4; ++cb)
#pragma unroll
      for (int kb = 0; kb < 4; ++kb)
        acc[cb] = mfma16(xa[kb], ldb(OFF_W1, tw * 16 + cb * 4 + kb), acc[cb]);

    if (tw == 2) {  // residual param tail (centered rows of rW1)
#pragma unroll
      for (int cb = 0; cb < 4; ++cb) {
        float w0 = g_rw1p[cb * 16 + lo];
        float w1 = g_rw1p[64 + cb * 16 + lo];
        float w2 = g_rw1p[128 + cb * 16 + lo];
#pragma unroll
        for (int r = 0; r < 4; ++r)
          acc[cb][r] = fmaf(pv[r][0], w0, fmaf(pv[r][1], w1, fmaf(pv[r][2], w2, acc[cb][r])));
      }
    }
    ln_write(acc, 4, g1, b1);

    half8 a0 = lda(0), a1 = lda(1);
    f32x4 o2[2];
#pragma unroll
    for (int cb = 0; cb < 2; ++cb)
      o2[cb] = mfma16(a1, ldb(w2off, cb * 2 + 1), mfma16(a0, ldb(w2off, cb * 2 + 0), z4));

    if (tw < 2) {
      const float* b2 = tw == 0 ? kb2 : vb2;
      float bv0 = b2[lo], bv1 = b2[16 + lo];
#pragma unroll
      for (int r = 0; r < 4; ++r) { o2[0][r] += bv0; o2[1][r] += bv1; }
      if (tw == 0) { kk[0] = o2[0]; kk[1] = o2[1]; }
      else         { vv[0] = o2[0]; vv[1] = o2[1]; }
    } else {
      ln_write(o2, 2, rg2, rb2);   // rW2 centered, no bias before LN
      float rb3v = rb3[lo];
      f32x4 o = mfma16(lda(0), ldb(OFF_RW3, 0), z4);
#pragma unroll
      for (int r = 0; r < 4; ++r) o[r] += rb3v;
      r16v = o;
    }
  }

  // ================= query tower =================
  f32x4 qq[2];
  {
    float qwv0 = g_qw1c[lo], qwv1 = g_qw1c[16 + lo], qwv2 = g_qw1c[32 + lo];
    f32x4 aq;
#pragma unroll
    for (int r = 0; r < 4; ++r)
      aq[r] = fmaf(pv[r][2], qwv2, fmaf(pv[r][1], qwv1, pv[r][0] * qwv0));
    ln_write(&aq, 1, qg1, qb1);
    // zero cols 16..31 so the padded-K A-frag is exactly zero
#pragma unroll
    for (int r = 0; r < 4; ++r)
      hw[(g4 * 4 + r) * HSTRIDE + 16 + lo] = (_Float16)0.f;
    float bv0 = qb2[lo], bv1 = qb2[16 + lo];
    half8 a0 = lda(0);
#pragma unroll
    for (int cb = 0; cb < 2; ++cb) {
      f32x4 o = mfma16(a0, ldb(OFF_QW2, cb), z4);
#pragma unroll
      for (int r = 0; r < 4; ++r) o[r] += (cb ? bv1 : bv0);
      qq[cb] = o;
    }
  }

  // ================= attention (raw exp: softmax shift-invariant; |s|~O(6)) ====
  f32x4 a16v;
  {
#pragma unroll
    for (int r = 0; r < 4; ++r) {
      float e0 = __expf(qq[0][r] * kk[0][r]);
      float e1 = __expf(qq[1][r] * kk[1][r]);
      float inv = 1.f / red16_sum(e0 + e1);
      hw[(g4 * 4 + r) * HSTRIDE + lo] = (_Float16)(e0 * inv * vv[0][r]);
      hw[(g4 * 4 + r) * HSTRIDE + 16 + lo] = (_Float16)(e1 * inv * vv[1][r]);
    }
    f32x4 h32[2];
    {
      half8 a0 = lda(0);
#pragma unroll
      for (int cb = 0; cb < 2; ++cb) h32[cb] = mfma16(a0, ldb(OFF_AW1, cb), z4);
    }
    ln_write(h32, 2, ag1, ab1);   // aW1 centered
    float ab2v = ab2[lo];
    f32x4 o = mfma16(lda(0), ldb(OFF_AW2, 0), z4);
#pragma unroll
    for (int r = 0; r < 4; ++r) o[r] += ab2v;
    a16v = o;
  }

  // ================= get_approach tower =================
  {
#pragma unroll
    for (int r = 0; r < 4; ++r) {
      hw[(g4 * 4 + r) * HSTRIDE + lo] = (_Float16)a16v[r];
      hw[(g4 * 4 + r) * HSTRIDE + 16 + lo] = (_Float16)r16v[r];
    }
    f32x4 f1 = mfma16(lda(0), ldb(OFF_GW1, 0), z4);   // gW1 centered
    ln_write(&f1, 1, gg1, gb1);
#pragma unroll
    for (int r = 0; r < 4; ++r)
      hw[(g4 * 4 + r) * HSTRIDE + 16 + lo] = (_Float16)0.f;
    float gb2v = (lo < 3) ? gb2[lo] : 0.f;
    f32x4 o = mfma16(lda(0), ldb(OFF_GW2, 0), z4);
    if (lo < 3) {
#pragma unroll
      for (int r = 0; r < 4; ++r)
        out[(size_t)(row0 + g4 * 4 + r) * 3 + lo] = o[r] + gb2v;
    }
  }
}

// ---------- launch ----------

extern "C" void kernel_launch(void* const* d_in, const int* in_sizes, int n_in,
                              void* d_out, int out_size, void* d_ws, size_t ws_size,
                              hipStream_t stream) {
  const float* rep = (const float*)d_in[0];
  const float* par = (const float*)d_in[1];
  const float* kW1 = (const float*)d_in[2];
  const float* kg1 = (const float*)d_in[3];
  const float* kb1 = (const float*)d_in[4];
  const float* kW2 = (const float*)d_in[5];
  const float* kb2 = (const float*)d_in[6];
  const float* qW1 = (const float*)d_in[7];
  const float* qg1 = (const float*)d_in[8];
  const float* qb1 = (const float*)d_in[9];
  const float* qW2 = (const float*)d_in[10];
  const float* qb2 = (const float*)d_in[11];
  const float* vW1 = (const float*)d_in[12];
  const float* vg1 = (const float*)d_in[13];
  const float* vb1 = (const float*)d_in[14];
  const float* vW2 = (const float*)d_in[15];
  const float* vb2 = (const float*)d_in[16];
  const float* aW1 = (const float*)d_in[17];
  const float* ag1 = (const float*)d_in[18];
  const float* ab1 = (const float*)d_in[19];
  const float* aW2 = (const float*)d_in[20];
  const float* ab2 = (const float*)d_in[21];
  const float* rW1 = (const float*)d_in[22];
  const float* rg1 = (const float*)d_in[23];
  const float* rb1 = (const float*)d_in[24];
  const float* rW2 = (const float*)d_in[25];
  const float* rg2 = (const float*)d_in[26];
  const float* rb2 = (const float*)d_in[27];
  const float* rW3 = (const float*)d_in[28];
  const float* rb3 = (const float*)d_in[29];
  const float* gW1 = (const float*)d_in[30];
  const float* gg1 = (const float*)d_in[31];
  const float* gb1 = (const float*)d_in[32];
  const float* gW2 = (const float*)d_in[33];
  const float* gb2 = (const float*)d_in[34];

  const int N = in_sizes[0] / 128;
  float* out = (float*)d_out;

  prepack_kernel<<<34, 256, 0, stream>>>(kW1, vW1, rW1, kW2, vW2, rW2,
                                         qW1, qW2, aW1, aW2, rW3, gW1, gW2);

  const int grid = (N + ROWS_PER_BLOCK - 1) / ROWS_PER_BLOCK;
  approach_mfma_kernel<<<grid, TPB, 0, stream>>>(
      rep, par,
      kg1, kb1, kb2,
      qg1, qb1, qb2,
      vg1, vb1, vb2,
      ag1, ab1, ab2,
      rg1, rb1, rg2, rb2, rb3,
      gg1, gb1, gb2,
      out, N);
}

// Round 9
// 304.875 us; speedup vs baseline: 1.5708x; 1.5708x over previous
//
#include <hip/hip_runtime.h>
#include <math.h>

#define LN_EPS 1e-5f
#define NWAVE 8
#define TPB 512
#define ROWS_PER_BLOCK 128   // 8 waves x 16 rows
#define HSTRIDE 72           // halves; 144B row stride (16B-aligned)

typedef _Float16 half8 __attribute__((ext_vector_type(8)));
typedef float f32x4 __attribute__((ext_vector_type(4)));

// weight-fragment table offsets (in halves); each fragment = 512 halves (64 lanes x 8)
#define OFF_W1   0        // [128x192] = kW1|vW1|rW1[0:128] centered, KB=4 -> 48 frags
#define OFF_KW2  24576    // [64x32] KB=2 CB=2 -> 4 frags
#define OFF_VW2  26624
#define OFF_RW2  28672    // centered
#define OFF_QW2  30720    // [16->pad32 x 32] KB=1 CB=2 (rows 16-31 zero)
#define OFF_AW1  31744    // [32x32] KB=1 CB=2, centered
#define OFF_AW2  32768    // [32x16] KB=1 CB=1
#define OFF_RW3  33280
#define OFF_GW1  33792    // centered
#define OFF_GW2  34304    // [16->pad32 x 3->pad16] zeros outside valid region
#define WL_HALVES 34816

__device__ _Float16 g_wfrag[WL_HALVES];  // L2-resident weight-fragment table (68 KB)
__device__ float g_rw1p[3 * 64];         // centered rW1 rows 128..130 (f32)
__device__ float g_qw1c[3 * 16];         // centered qW1 (f32)

__device__ __forceinline__ f32x4 mfma16(half8 a, half8 b, f32x4 c) {
  return __builtin_amdgcn_mfma_f32_16x16x32_f16(a, b, c, 0, 0, 0);
}

// ---- DPP 16-lane sum (pure VALU; proven R5-R8) ----
template<int CTRL>
__device__ __forceinline__ float dpp_mov(float x) {
  int xi = __builtin_bit_cast(int, x);
  int yi = __builtin_amdgcn_update_dpp(xi, xi, CTRL, 0xF, 0xF, false);
  return __builtin_bit_cast(float, yi);
}
__device__ __forceinline__ float red16_sum(float x) {
  x += dpp_mov<0xB1>(x);    // xor1: quad_perm(1,0,3,2)
  x += dpp_mov<0x4E>(x);    // xor2: quad_perm(2,3,0,1)
  x += dpp_mov<0x141>(x);   // xor4: ROW_HALF_MIRROR
  x += dpp_mov<0x140>(x);   // xor8: ROW_MIRROR
  return x;
}

// fp32 [K][N] row-major weight -> B-fragment order; optional per-k-row column-mean
// centering (valid: every LN input is a bias-free linear output, LN is shift-invariant
// in its input mean; proven absmax-neutral in R8).
__device__ __forceinline__ void pack_frag(const float* __restrict__ W,
    int Ksrc, int Nsrc, int Kpad, int Npad, int KBdst, int cb_off,
    int off, int gtid, int gstride, bool center) {
  int tot = Kpad * Npad;
  float rn = 1.f / (float)Nsrc;
  for (int idx = gtid; idx < tot; idx += gstride) {
    int k = idx / Npad;
    int c = idx - k * Npad;
    float v = 0.f;
    if (k < Ksrc && c < Nsrc) {
      v = W[k * Nsrc + c];
      if (center) {
        float m = 0.f;
        for (int c2 = 0; c2 < Nsrc; ++c2) m += W[k * Nsrc + c2];
        v -= m * rn;
      }
    }
    int cb = cb_off + (c >> 4);
    int lanei = ((k >> 3) & 3) * 16 + (c & 15);
    int dst = off + ((cb * KBdst + (k >> 5)) * 64 + lanei) * 8 + (k & 7);
    g_wfrag[dst] = (_Float16)v;
  }
}

__global__ void prepack_kernel(const float* kW1, const float* vW1, const float* rW1,
                               const float* kW2, const float* vW2, const float* rW2,
                               const float* qW1, const float* qW2, const float* aW1,
                               const float* aW2, const float* rW3, const float* gW1,
                               const float* gW2) {
  int gtid = blockIdx.x * blockDim.x + threadIdx.x;
  int gstride = gridDim.x * blockDim.x;
  pack_frag(kW1, 128, 64, 128, 64, 4, 0, OFF_W1, gtid, gstride, true);
  pack_frag(vW1, 128, 64, 128, 64, 4, 4, OFF_W1, gtid, gstride, true);
  pack_frag(rW1, 128, 64, 128, 64, 4, 8, OFF_W1, gtid, gstride, true);  // rows 0..127
  pack_frag(kW2, 64, 32, 64, 32, 2, 0, OFF_KW2, gtid, gstride, false);
  pack_frag(vW2, 64, 32, 64, 32, 2, 0, OFF_VW2, gtid, gstride, false);
  pack_frag(rW2, 64, 32, 64, 32, 2, 0, OFF_RW2, gtid, gstride, true);
  pack_frag(qW2, 16, 32, 32, 32, 1, 0, OFF_QW2, gtid, gstride, false);
  pack_frag(aW1, 32, 32, 32, 32, 1, 0, OFF_AW1, gtid, gstride, true);
  pack_frag(aW2, 32, 16, 32, 16, 1, 0, OFF_AW2, gtid, gstride, false);
  pack_frag(rW3, 32, 16, 32, 16, 1, 0, OFF_RW3, gtid, gstride, false);
  pack_frag(gW1, 32, 16, 32, 16, 1, 0, OFF_GW1, gtid, gstride, true);
  pack_frag(gW2, 16, 3, 32, 16, 1, 0, OFF_GW2, gtid, gstride, false);
  // centered rW1 param rows 128..130 (over the row's 64 cols)
  for (int i = gtid; i < 3 * 64; i += gstride) {
    int k = 128 + i / 64, c = i - (i / 64) * 64;
    float m = 0.f;
    for (int c2 = 0; c2 < 64; ++c2) m += rW1[k * 64 + c2];
    g_rw1p[i] = rW1[k * 64 + c] - m * (1.f / 64.f);
  }
  // centered qW1 (over 16 cols)
  for (int i = gtid; i < 3 * 16; i += gstride) {
    int k = i / 16, c = i - (i / 16) * 16;
    float m = 0.f;
    for (int c2 = 0; c2 < 16; ++c2) m += qW1[k * 16 + c2];
    g_qw1c[i] = qW1[k * 16 + c] - m * (1.f / 16.f);
  }
}

__global__ __launch_bounds__(TPB, 6)
void approach_mfma_kernel(
    const float* __restrict__ rep, const float* __restrict__ par,
    const float* __restrict__ kg1, const float* __restrict__ kb1, const float* __restrict__ kb2,
    const float* __restrict__ qg1, const float* __restrict__ qb1, const float* __restrict__ qb2,
    const float* __restrict__ vg1, const float* __restrict__ vb1, const float* __restrict__ vb2,
    const float* __restrict__ ag1, const float* __restrict__ ab1, const float* __restrict__ ab2,
    const float* __restrict__ rg1, const float* __restrict__ rb1,
    const float* __restrict__ rg2, const float* __restrict__ rb2, const float* __restrict__ rb3,
    const float* __restrict__ gg1, const float* __restrict__ gb1, const float* __restrict__ gb2,
    float* __restrict__ out, int N)
{
  __shared__ __align__(16) _Float16 hs[NWAVE][16][HSTRIDE];

  const int tid = threadIdx.x;
  const int wave = tid >> 6;
  const int lane = tid & 63;
  const int lo = lane & 15;     // A-row / D-col / B-col index
  const int g4 = lane >> 4;     // k-subblock / D-row group
  const long long row0 = (long long)blockIdx.x * ROWS_PER_BLOCK + wave * 16;
  if (row0 + 16 > N) return;

  _Float16* hw = &hs[wave][0][0];  // [16][HSTRIDE]

  auto ldb = [&](int off, int frag) -> half8 {
    return *reinterpret_cast<const half8*>(&g_wfrag[off + frag * 512 + lane * 8]);
  };
  auto lda = [&](int kb) -> half8 {
    return *reinterpret_cast<const half8*>(&hw[lo * HSTRIDE + kb * 32 + g4 * 8]);
  };
  const f32x4 z4 = {0.f, 0.f, 0.f, 0.f};

  // LN (mean-free: inputs centered by construction) + affine + ReLU, D-layout -> f16 LDS
  auto ln_write = [&](const f32x4* acc, int CB, const float* __restrict__ g,
                      const float* __restrict__ b) {
#pragma unroll 4
    for (int r = 0; r < 4; ++r) {
      float q = 0.f;
      for (int cb = 0; cb < CB; ++cb) { float x = acc[cb][r]; q = fmaf(x, x, q); }
      q = red16_sum(q);
      float rstd = rsqrtf(q * (1.f / (16.f * CB)) + LN_EPS);
      for (int cb = 0; cb < CB; ++cb) {
        float h = fmaxf(fmaf(acc[cb][r] * rstd, g[cb * 16 + lo], b[cb * 16 + lo]), 0.f);
        hw[(g4 * 4 + r) * HSTRIDE + cb * 16 + lo] = (_Float16)h;
      }
    }
  };

  // ---- x A-fragments: row = row0 + lo, k = kb*32 + g4*8 + j
  half8 xa[4];
  {
    const float* xr = rep + (size_t)(row0 + lo) * 128 + g4 * 8;
#pragma unroll
    for (int kb = 0; kb < 4; ++kb) {
      f32x4 u0 = *reinterpret_cast<const f32x4*>(xr + kb * 32);
      f32x4 u1 = *reinterpret_cast<const f32x4*>(xr + kb * 32 + 4);
      half8 h;
#pragma unroll
      for (int j = 0; j < 4; ++j) { h[j] = (_Float16)u0[j]; h[4 + j] = (_Float16)u1[j]; }
      xa[kb] = h;
    }
  }

  f32x4 kk[2], vv[2], qq[2], a16v, r16v;

  // ================= key tower =================
  {
    f32x4 acc[4] = {z4, z4, z4, z4};
#pragma unroll
    for (int cb = 0; cb < 4; ++cb)
#pragma unroll
      for (int kb = 0; kb < 4; ++kb)
        acc[cb] = mfma16(xa[kb], ldb(OFF_W1, (0 * 4 + cb) * 4 + kb), acc[cb]);
    ln_write(acc, 4, kg1, kb1);
    float biasv[2] = {kb2[lo], kb2[16 + lo]};
    half8 a0 = lda(0), a1 = lda(1);
#pragma unroll
    for (int cb = 0; cb < 2; ++cb) {
      f32x4 o = mfma16(a0, ldb(OFF_KW2, cb * 2 + 0), z4);
      o = mfma16(a1, ldb(OFF_KW2, cb * 2 + 1), o);
#pragma unroll
      for (int r = 0; r < 4; ++r) o[r] += biasv[cb];
      kk[cb] = o;
    }
  }

  // ================= value tower =================
  {
    f32x4 acc[4] = {z4, z4, z4, z4};
#pragma unroll
    for (int cb = 0; cb < 4; ++cb)
#pragma unroll
      for (int kb = 0; kb < 4; ++kb)
        acc[cb] = mfma16(xa[kb], ldb(OFF_W1, (1 * 4 + cb) * 4 + kb), acc[cb]);
    ln_write(acc, 4, vg1, vb1);
    float biasv[2] = {vb2[lo], vb2[16 + lo]};
    half8 a0 = lda(0), a1 = lda(1);
#pragma unroll
    for (int cb = 0; cb < 2; ++cb) {
      f32x4 o = mfma16(a0, ldb(OFF_VW2, cb * 2 + 0), z4);
      o = mfma16(a1, ldb(OFF_VW2, cb * 2 + 1), o);
#pragma unroll
      for (int r = 0; r < 4; ++r) o[r] += biasv[cb];
      vv[cb] = o;
    }
  }

  // ---- parameters for this tile's D-rows (row = row0 + g4*4 + r), loaded late
  float pv[4][3];
#pragma unroll
  for (int r = 0; r < 4; ++r) {
    size_t prow = (size_t)(row0 + g4 * 4 + r) * 3;
#pragma unroll
    for (int i = 0; i < 3; ++i) pv[r][i] = par[prow + i];
  }

  // ================= residuals tower =================
  {
    f32x4 acc[4] = {z4, z4, z4, z4};
#pragma unroll
    for (int cb = 0; cb < 4; ++cb)
#pragma unroll
      for (int kb = 0; kb < 4; ++kb)
        acc[cb] = mfma16(xa[kb], ldb(OFF_W1, (2 * 4 + cb) * 4 + kb), acc[cb]);
    // + centered parameter rows 128..130 of rW1 (D-layout elementwise)
#pragma unroll
    for (int cb = 0; cb < 4; ++cb) {
      float w0 = g_rw1p[cb * 16 + lo];
      float w1 = g_rw1p[64 + cb * 16 + lo];
      float w2 = g_rw1p[128 + cb * 16 + lo];
#pragma unroll
      for (int r = 0; r < 4; ++r)
        acc[cb][r] = fmaf(pv[r][0], w0, fmaf(pv[r][1], w1, fmaf(pv[r][2], w2, acc[cb][r])));
    }
    ln_write(acc, 4, rg1, rb1);
    f32x4 r32[2];
    {
      half8 a0 = lda(0), a1 = lda(1);
#pragma unroll
      for (int cb = 0; cb < 2; ++cb) {
        f32x4 o = mfma16(a0, ldb(OFF_RW2, cb * 2 + 0), z4);
        o = mfma16(a1, ldb(OFF_RW2, cb * 2 + 1), o);
        r32[cb] = o;  // rW2 centered; no bias before LN
      }
    }
    ln_write(r32, 2, rg2, rb2);
    float rb3v = rb3[lo];
    f32x4 o = mfma16(lda(0), ldb(OFF_RW3, 0), z4);
#pragma unroll
    for (int r = 0; r < 4; ++r) o[r] += rb3v;
    r16v = o;
  }

  // ================= query tower =================
  {
    float qwv0 = g_qw1c[lo], qwv1 = g_qw1c[16 + lo], qwv2 = g_qw1c[32 + lo];
    f32x4 aq;
#pragma unroll
    for (int r = 0; r < 4; ++r)
      aq[r] = fmaf(pv[r][2], qwv2, fmaf(pv[r][1], qwv1, pv[r][0] * qwv0));
    ln_write(&aq, 1, qg1, qb1);
    // zero cols 16..31 so the padded-K A-frag is exactly zero
#pragma unroll
    for (int r = 0; r < 4; ++r)
      hw[(g4 * 4 + r) * HSTRIDE + 16 + lo] = (_Float16)0.f;
    float biasv[2] = {qb2[lo], qb2[16 + lo]};
    half8 a0 = lda(0);
#pragma unroll
    for (int cb = 0; cb < 2; ++cb) {
      f32x4 o = mfma16(a0, ldb(OFF_QW2, cb), z4);
#pragma unroll
      for (int r = 0; r < 4; ++r) o[r] += biasv[cb];
      qq[cb] = o;
    }
  }

  // ====== attention (raw exp: softmax shift-invariant, |s| small; proven R8) ======
  {
#pragma unroll
    for (int r = 0; r < 4; ++r) {
      float e0 = __expf(qq[0][r] * kk[0][r]);
      float e1 = __expf(qq[1][r] * kk[1][r]);
      float inv = 1.f / red16_sum(e0 + e1);
      hw[(g4 * 4 + r) * HSTRIDE + lo] = (_Float16)(e0 * inv * vv[0][r]);
      hw[(g4 * 4 + r) * HSTRIDE + 16 + lo] = (_Float16)(e1 * inv * vv[1][r]);
    }
    f32x4 h32[2];
    {
      half8 a0 = lda(0);
#pragma unroll
      for (int cb = 0; cb < 2; ++cb) h32[cb] = mfma16(a0, ldb(OFF_AW1, cb), z4);
    }
    ln_write(h32, 2, ag1, ab1);   // aW1 centered
    float ab2v = ab2[lo];
    f32x4 o = mfma16(lda(0), ldb(OFF_AW2, 0), z4);
#pragma unroll
    for (int r = 0; r < 4; ++r) o[r] += ab2v;
    a16v = o;
  }

  // ================= get_approach tower =================
  {
#pragma unroll
    for (int r = 0; r < 4; ++r) {
      hw[(g4 * 4 + r) * HSTRIDE + lo] = (_Float16)a16v[r];
      hw[(g4 * 4 + r) * HSTRIDE + 16 + lo] = (_Float16)r16v[r];
    }
    f32x4 f1 = mfma16(lda(0), ldb(OFF_GW1, 0), z4);   // gW1 centered
    ln_write(&f1, 1, gg1, gb1);
#pragma unroll
    for (int r = 0; r < 4; ++r)
      hw[(g4 * 4 + r) * HSTRIDE + 16 + lo] = (_Float16)0.f;
    float gb2v = (lo < 3) ? gb2[lo] : 0.f;
    f32x4 o = mfma16(lda(0), ldb(OFF_GW2, 0), z4);
    if (lo < 3) {
#pragma unroll
      for (int r = 0; r < 4; ++r)
        out[(size_t)(row0 + g4 * 4 + r) * 3 + lo] = o[r] + gb2v;
    }
  }
}

// ---------- launch ----------

extern "C" void kernel_launch(void* const* d_in, const int* in_sizes, int n_in,
                              void* d_out, int out_size, void* d_ws, size_t ws_size,
                              hipStream_t stream) {
  const float* rep = (const float*)d_in[0];
  const float* par = (const float*)d_in[1];
  const float* kW1 = (const float*)d_in[2];
  const float* kg1 = (const float*)d_in[3];
  const float* kb1 = (const float*)d_in[4];
  const float* kW2 = (const float*)d_in[5];
  const float* kb2 = (const float*)d_in[6];
  const float* qW1 = (const float*)d_in[7];
  const float* qg1 = (const float*)d_in[8];
  const float* qb1 = (const float*)d_in[9];
  const float* qW2 = (const float*)d_in[10];
  const float* qb2 = (const float*)d_in[11];
  const float* vW1 = (const float*)d_in[12];
  const float* vg1 = (const float*)d_in[13];
  const float* vb1 = (const float*)d_in[14];
  const float* vW2 = (const float*)d_in[15];
  const float* vb2 = (const float*)d_in[16];
  const float* aW1 = (const float*)d_in[17];
  const float* ag1 = (const float*)d_in[18];
  const float* ab1 = (const float*)d_in[19];
  const float* aW2 = (const float*)d_in[20];
  const float* ab2 = (const float*)d_in[21];
  const float* rW1 = (const float*)d_in[22];
  const float* rg1 = (const float*)d_in[23];
  const float* rb1 = (const float*)d_in[24];
  const float* rW2 = (const float*)d_in[25];
  const float* rg2 = (const float*)d_in[26];
  const float* rb2 = (const float*)d_in[27];
  const float* rW3 = (const float*)d_in[28];
  const float* rb3 = (const float*)d_in[29];
  const float* gW1 = (const float*)d_in[30];
  const float* gg1 = (const float*)d_in[31];
  const float* gb1 = (const float*)d_in[32];
  const float* gW2 = (const float*)d_in[33];
  const float* gb2 = (const float*)d_in[34];

  const int N = in_sizes[0] / 128;
  float* out = (float*)d_out;

  prepack_kernel<<<34, 256, 0, stream>>>(kW1, vW1, rW1, kW2, vW2, rW2,
                                         qW1, qW2, aW1, aW2, rW3, gW1, gW2);

  const int grid = (N + ROWS_PER_BLOCK - 1) / ROWS_PER_BLOCK;
  approach_mfma_kernel<<<grid, TPB, 0, stream>>>(
      rep, par,
      kg1, kb1, kb2,
      qg1, qb1, qb2,
      vg1, vb1, vb2,
      ag1, ab1, ab2,
      rg1, rb1, rg2, rb2, rb3,
      gg1, gb1, gb2,
      out, N);
}